// Round 13
// baseline (608.860 us; speedup 1.0000x reference)
//
#include <hip/hip_runtime.h>
#include <hip/hip_bf16.h>
#include <math.h>

#define NN 8192
#define CH 256
#define NDIST 2080
#define NTOT  2592            // 2080 dist + 512 gemm_h
#define NMERGE 256            // last-256 ticket holders run the merge tail

typedef unsigned long long u64;
typedef __attribute__((ext_vector_type(8))) short s16x8;
typedef __attribute__((ext_vector_type(4))) float f32x4;

__device__ __forceinline__ u64 pack_di(float d, unsigned j) {
    unsigned u = __float_as_uint(d);
    u ^= (unsigned)((int)u >> 31) | 0x80000000u;
    return ((u64)u << 32) | (u64)j;
}

__device__ __forceinline__ void ins3(u64 &t0, u64 &t1, u64 &t2, u64 v) {
    bool c0 = v < t0;
    u64 hi0 = c0 ? t0 : v;
    t0      = c0 ? v  : t0;
    bool c1 = hi0 < t1;
    u64 hi1 = c1 ? t1 : hi0;
    t1      = c1 ? hi0 : t1;
    t2      = hi1 < t2 ? hi1 : t2;
}

__device__ __forceinline__ u64 umin64(u64 a, u64 b) { return a < b ? a : b; }
__device__ __forceinline__ u64 umax64(u64 a, u64 b) { return a < b ? b : a; }

__device__ __forceinline__ void merge3(u64 &a0, u64 &a1, u64 &a2, u64 b0, u64 b1, u64 b2) {
    u64 m0 = umin64(a0, b0), M0 = umax64(a0, b0);
    u64 m1 = umin64(a1, b1);
    u64 m2 = umin64(a2, b2);
    u64 s  = umin64(M0, m1), S = umax64(M0, m1);
    a0 = m0;
    a1 = s;
    a2 = umin64(S, m2);
}

__device__ __forceinline__ void gl_lds16(const void* g, void* l) {
    __builtin_amdgcn_global_load_lds(
        (const __attribute__((address_space(1))) unsigned int*)g,
        (__attribute__((address_space(3))) unsigned int*)l, 16, 0, 0);
}

// ---------------- splits ----------------
__device__ __forceinline__ void split1(float a, unsigned short& h, unsigned short& m, unsigned short& l) {
    __hip_bfloat16 bh = __float2bfloat16(a);
    float fh = __bfloat162float(bh);
    float r = a - fh;
    __hip_bfloat16 bm = __float2bfloat16(r);
    float fm = __bfloat162float(bm);
    __hip_bfloat16 bl = __float2bfloat16(r - fm);
    h = *(unsigned short*)&bh; m = *(unsigned short*)&bm; l = *(unsigned short*)&bl;
}

__device__ __forceinline__ void split2one(float a, unsigned short& h, unsigned short& m) {
    __hip_bfloat16 bh = __float2bfloat16(a);
    float r = a - __bfloat162float(bh);
    __hip_bfloat16 bm = __float2bfloat16(r);
    h = *(unsigned short*)&bh; m = *(unsigned short*)&bm;
}

// ------- fused: softmax + sq + split3(p) + split2(x) + outp/done zeroing + weight splits --
__global__ __launch_bounds__(256) void softmax_split_kernel(
    const float* __restrict__ x, float* __restrict__ sq,
    unsigned short* __restrict__ pa, unsigned short* __restrict__ pb,
    unsigned short* __restrict__ pc, unsigned short* __restrict__ xh,
    unsigned short* __restrict__ xm, float* __restrict__ outp, int* __restrict__ done,
    const float* __restrict__ W1, const float* __restrict__ Wrel, const float* __restrict__ Wroot,
    unsigned short* __restrict__ d0h, unsigned short* __restrict__ d0m,
    unsigned short* __restrict__ d1h, unsigned short* __restrict__ d1m,
    unsigned short* __restrict__ d2h, unsigned short* __restrict__ d2m)
{
    if (blockIdx.x >= NN / 4) {
        int wb = blockIdx.x - NN / 4;      // 0..191
        int which = wb >> 6;
        const float* s = (which == 0) ? W1 : (which == 1) ? Wrel : Wroot;
        unsigned short* dh = (which == 0) ? d0h : (which == 1) ? d1h : d2h;
        unsigned short* dm = (which == 0) ? d0m : (which == 1) ? d1m : d2m;
        int i = (wb & 63) * 1024 + threadIdx.x * 4;
        float4 v = *(const float4*)(s + i);
        ushort4 H, M;
        split2one(v.x, H.x, M.x);
        split2one(v.y, H.y, M.y);
        split2one(v.z, H.z, M.z);
        split2one(v.w, H.w, M.w);
        *(ushort4*)(dh + i) = H;
        *(ushort4*)(dm + i) = M;
        return;
    }
    if (blockIdx.x == 0 && threadIdx.x == 0) *done = 0;   // ticket counter for fused dispatch
    int wave = threadIdx.x >> 6, lane = threadIdx.x & 63;
    int row = blockIdx.x * 4 + wave;
    if (lane == 1) {    // zero the linear2 accumulators for this row (gemm2 is atomic)
        outp[row * 2 + 0] = 0.0f;
        outp[row * 2 + 1] = 0.0f;
    }
    const float4* xr = (const float4*)(x + (size_t)row * CH);
    float4 v = xr[lane];
    int i = row * CH + lane * 4;
    ushort4 XH, XM;
    split2one(v.x, XH.x, XM.x);
    split2one(v.y, XH.y, XM.y);
    split2one(v.z, XH.z, XM.z);
    split2one(v.w, XH.w, XM.w);
    *(ushort4*)(xh + i) = XH;
    *(ushort4*)(xm + i) = XM;
    float m = fmaxf(fmaxf(v.x, v.y), fmaxf(v.z, v.w));
    #pragma unroll
    for (int off = 32; off; off >>= 1) m = fmaxf(m, __shfl_xor(m, off, 64));
    float e0 = expf(v.x - m), e1 = expf(v.y - m), e2 = expf(v.z - m), e3 = expf(v.w - m);
    float s = (e0 + e1) + (e2 + e3);
    #pragma unroll
    for (int off = 32; off; off >>= 1) s += __shfl_xor(s, off, 64);
    float p0 = e0 / s, p1 = e1 / s, p2 = e2 / s, p3 = e3 / s;
    float qv = (p0 * p0 + p1 * p1) + (p2 * p2 + p3 * p3);
    #pragma unroll
    for (int off = 32; off; off >>= 1) qv += __shfl_xor(qv, off, 64);
    if (lane == 0) sq[row] = qv;
    ushort4 H, M, L;
    split1(p0, H.x, M.x, L.x);
    split1(p1, H.y, M.y, L.y);
    split1(p2, H.z, M.z, L.z);
    split1(p3, H.w, M.w, L.w);
    *(ushort4*)(pa + i) = H;
    *(ushort4*)(pb + i) = M;
    *(ushort4*)(pc + i) = L;
}

// ===== FUSED dispatch: [0,2080) dist tiles; [2080,2592) gemm_h; ticketed merge tail =====
// dist: 128x128 triangular tile, 4 waves (2x2), 6 products; single-barrier epilogue.
// gemm_h: 64x64 tile, h = relu(x @ W1^T + b1) + bf16 split of h.
// Tail: last NMERGE ticket holders spin until all 2592 blocks done, then each merges
// 32 rows of `part` + gathers h + emits agg splits (replaces the merge_gather launch).
__global__ __launch_bounds__(256, 3) void dist_gemmh_fused(
    const unsigned short* __restrict__ pa, const unsigned short* __restrict__ pb,
    const unsigned short* __restrict__ pc, const float* __restrict__ sq,
    u64* __restrict__ part,
    const unsigned short* __restrict__ Ah, const unsigned short* __restrict__ Am,
    const unsigned short* __restrict__ Wh, const unsigned short* __restrict__ Wm,
    const float* __restrict__ bias, float* __restrict__ hout,
    unsigned short* __restrict__ oh, unsigned short* __restrict__ om,
    unsigned short* __restrict__ gh, unsigned short* __restrict__ gm,
    int* __restrict__ done)
{
    __shared__ short sA[3][128 * 32];
    __shared__ short sB[3][128 * 32];
    __shared__ int tk_s;

    int tid = threadIdx.x;
    int wave = tid >> 6, lane = tid & 63;
    int lc = lane & 15, q = lane >> 4;
    int srow = lane >> 2;
    int skq  = ((lane & 3) ^ ((lane >> 3) & 3)) * 8;   // XOR-swizzled global 16B slot
    int cq   = (q ^ ((lc >> 1) & 3)) * 8;              // swizzled LDS slot for frag reads

    if (blockIdx.x >= NDIST) {
        // ---------------- gemm_h branch ----------------
        int b = blockIdx.x - NDIST;                    // 0..511
        int mbase = (b & 127) * 64, nbase = (b >> 7) * 64;
        short* sAh = &sA[0][0];
        short* sAm = &sA[0][64 * 32];
        short* sBh = &sA[1][0];
        short* sBm = &sA[1][64 * 32];

        f32x4 acc[4];
        #pragma unroll
        for (int nt = 0; nt < 4; ++nt) acc[nt] = (f32x4){0.f, 0.f, 0.f, 0.f};

        int r0 = wave * 16;
        const unsigned short* gsrc[4];
        short* ldst[4];
        gsrc[0] = Ah + (size_t)(mbase + r0 + srow) * CH + skq;  ldst[0] = &sAh[r0 * 32];
        gsrc[1] = Am + (size_t)(mbase + r0 + srow) * CH + skq;  ldst[1] = &sAm[r0 * 32];
        gsrc[2] = Wh + (size_t)(nbase + r0 + srow) * CH + skq;  ldst[2] = &sBh[r0 * 32];
        gsrc[3] = Wm + (size_t)(nbase + r0 + srow) * CH + skq;  ldst[3] = &sBm[r0 * 32];

        for (int kk = 0; kk < CH; kk += 32) {
            #pragma unroll
            for (int t = 0; t < 4; ++t) { gl_lds16(gsrc[t], ldst[t]); gsrc[t] += 32; }
            __syncthreads();
            s16x8 aH, aM, bH[4], bM[4];
            aH = *(const s16x8*)&sAh[(wave * 16 + lc) * 32 + cq];
            aM = *(const s16x8*)&sAm[(wave * 16 + lc) * 32 + cq];
            #pragma unroll
            for (int nt = 0; nt < 4; ++nt) {
                bH[nt] = *(const s16x8*)&sBh[(nt * 16 + lc) * 32 + cq];
                bM[nt] = *(const s16x8*)&sBm[(nt * 16 + lc) * 32 + cq];
            }
            #pragma unroll
            for (int nt = 0; nt < 4; ++nt)
                acc[nt] = __builtin_amdgcn_mfma_f32_16x16x32_bf16(aH, bH[nt], acc[nt], 0, 0, 0);
            #pragma unroll
            for (int nt = 0; nt < 4; ++nt)
                acc[nt] = __builtin_amdgcn_mfma_f32_16x16x32_bf16(aH, bM[nt], acc[nt], 0, 0, 0);
            #pragma unroll
            for (int nt = 0; nt < 4; ++nt)
                acc[nt] = __builtin_amdgcn_mfma_f32_16x16x32_bf16(aM, bH[nt], acc[nt], 0, 0, 0);
            __syncthreads();
        }

        #pragma unroll
        for (int nt = 0; nt < 4; ++nt) {
            float bv = bias[nbase + nt * 16 + lc];
            #pragma unroll
            for (int rg = 0; rg < 4; ++rg) {
                int row = mbase + wave * 16 + q * 4 + rg;
                int col = nbase + nt * 16 + lc;
                float v = fmaxf(acc[nt][rg] + bv, 0.0f);
                hout[(size_t)row * CH + col] = v;
                unsigned short hh_, hm_;
                split2one(v, hh_, hm_);
                oh[(size_t)row * CH + col] = hh_;
                om[(size_t)row * CH + col] = hm_;
            }
        }
    } else {
        // ---------------- dist branch (compact triangular id) ----------------
        u64* rowbuf = (u64*)&sA[0][0];      // 128 x 2 triples (sA dead post K-loop)
        u64* colbuf = rowbuf + 128 * 6;
        int t = blockIdx.x;
        int it = 0;
        while (t >= 64 - it) { t -= 64 - it; ++it; }
        int jt = it + t;
        bool diag = (jt == it);
        int wi = wave >> 1, wj = wave & 1;
        int ibase = it * 128, jbase = jt * 128;

        f32x4 acc[4][4];
        #pragma unroll
        for (int mt = 0; mt < 4; ++mt)
            #pragma unroll
            for (int nt = 0; nt < 4; ++nt)
                acc[mt][nt] = (f32x4){0.f, 0.f, 0.f, 0.f};

        const unsigned short* gsrc[12];
        short* ldst[12];
        {
            const unsigned short* comp[3] = {pa, pb, pc};
            #pragma unroll
            for (int c = 0; c < 3; ++c)
                #pragma unroll
                for (int ch = 0; ch < 2; ++ch) {
                    int r0 = (wave * 2 + ch) * 16;
                    int n = (c * 2 + ch) * 2;
                    gsrc[n + 0] = comp[c] + (size_t)(ibase + r0 + srow) * CH + skq;
                    ldst[n + 0] = &sA[c][r0 * 32];
                    gsrc[n + 1] = comp[c] + (size_t)(jbase + r0 + srow) * CH + skq;
                    ldst[n + 1] = &sB[c][r0 * 32];
                }
        }

        for (int kk = 0; kk < CH; kk += 32) {
            #pragma unroll
            for (int t2 = 0; t2 < 12; ++t2) { gl_lds16(gsrc[t2], ldst[t2]); gsrc[t2] += 32; }
            __syncthreads();

            s16x8 aH[4], bH[4], aM[4], bM[4], aL[4], bL[4];
            #pragma unroll
            for (int mt = 0; mt < 4; ++mt)
                aH[mt] = *(const s16x8*)&sA[0][(wi * 64 + mt * 16 + lc) * 32 + cq];
            #pragma unroll
            for (int nt = 0; nt < 4; ++nt)
                bH[nt] = *(const s16x8*)&sB[0][(wj * 64 + nt * 16 + lc) * 32 + cq];
            #pragma unroll
            for (int mt = 0; mt < 4; ++mt)
                #pragma unroll
                for (int nt = 0; nt < 4; ++nt)
                    acc[mt][nt] = __builtin_amdgcn_mfma_f32_16x16x32_bf16(aH[mt], bH[nt], acc[mt][nt], 0, 0, 0);

            #pragma unroll
            for (int nt = 0; nt < 4; ++nt)
                bM[nt] = *(const s16x8*)&sB[1][(wj * 64 + nt * 16 + lc) * 32 + cq];
            #pragma unroll
            for (int mt = 0; mt < 4; ++mt)
                #pragma unroll
                for (int nt = 0; nt < 4; ++nt)
                    acc[mt][nt] = __builtin_amdgcn_mfma_f32_16x16x32_bf16(aH[mt], bM[nt], acc[mt][nt], 0, 0, 0);

            #pragma unroll
            for (int mt = 0; mt < 4; ++mt)
                aM[mt] = *(const s16x8*)&sA[1][(wi * 64 + mt * 16 + lc) * 32 + cq];
            #pragma unroll
            for (int mt = 0; mt < 4; ++mt)
                #pragma unroll
                for (int nt = 0; nt < 4; ++nt)
                    acc[mt][nt] = __builtin_amdgcn_mfma_f32_16x16x32_bf16(aM[mt], bH[nt], acc[mt][nt], 0, 0, 0);
            #pragma unroll
            for (int mt = 0; mt < 4; ++mt)
                #pragma unroll
                for (int nt = 0; nt < 4; ++nt)
                    acc[mt][nt] = __builtin_amdgcn_mfma_f32_16x16x32_bf16(aM[mt], bM[nt], acc[mt][nt], 0, 0, 0);

            #pragma unroll
            for (int nt = 0; nt < 4; ++nt)
                bL[nt] = *(const s16x8*)&sB[2][(wj * 64 + nt * 16 + lc) * 32 + cq];
            #pragma unroll
            for (int mt = 0; mt < 4; ++mt)
                #pragma unroll
                for (int nt = 0; nt < 4; ++nt)
                    acc[mt][nt] = __builtin_amdgcn_mfma_f32_16x16x32_bf16(aH[mt], bL[nt], acc[mt][nt], 0, 0, 0);

            #pragma unroll
            for (int mt = 0; mt < 4; ++mt)
                aL[mt] = *(const s16x8*)&sA[2][(wi * 64 + mt * 16 + lc) * 32 + cq];
            #pragma unroll
            for (int mt = 0; mt < 4; ++mt)
                #pragma unroll
                for (int nt = 0; nt < 4; ++nt)
                    acc[mt][nt] = __builtin_amdgcn_mfma_f32_16x16x32_bf16(aL[mt], bH[nt], acc[mt][nt], 0, 0, 0);

            __syncthreads();
        }

        // ---- epilogue: D = (sq_i + sq_j) - 2*dot; single barrier + distributed tail ----
        float sqjv[4];
        #pragma unroll
        for (int nt = 0; nt < 4; ++nt) sqjv[nt] = sq[jbase + wj * 64 + nt * 16 + lc];
        float sqiv[4][4];
        #pragma unroll
        for (int mt = 0; mt < 4; ++mt)
            #pragma unroll
            for (int rg = 0; rg < 4; ++rg)
                sqiv[mt][rg] = sq[ibase + wi * 64 + mt * 16 + q * 4 + rg];

        #pragma unroll
        for (int mt = 0; mt < 4; ++mt) {
            #pragma unroll
            for (int rg = 0; rg < 4; ++rg) {
                float sqi = sqiv[mt][rg];
                u64 t0 = ~0ULL, t1 = ~0ULL, t2 = ~0ULL;
                #pragma unroll
                for (int nt = 0; nt < 4; ++nt) {
                    float dv = (sqi + sqjv[nt]) - 2.0f * acc[mt][nt][rg];
                    unsigned col = (unsigned)(jbase + wj * 64 + nt * 16 + lc);
                    ins3(t0, t1, t2, pack_di(dv, col));
                }
                #pragma unroll
                for (int m = 1; m < 16; m <<= 1) {
                    u64 b0 = __shfl_xor(t0, m, 64);
                    u64 b1 = __shfl_xor(t1, m, 64);
                    u64 b2 = __shfl_xor(t2, m, 64);
                    merge3(t0, t1, t2, b0, b1, b2);
                }
                if (lc == 0) {
                    int r = wi * 64 + mt * 16 + q * 4 + rg;
                    u64* rb = &rowbuf[r * 6 + wj * 3];
                    rb[0] = t0; rb[1] = t1; rb[2] = t2;
                }
            }
        }

        if (!diag) {
            u64 ct[4][3];
            #pragma unroll
            for (int nt = 0; nt < 4; ++nt) { ct[nt][0] = ~0ULL; ct[nt][1] = ~0ULL; ct[nt][2] = ~0ULL; }
            #pragma unroll
            for (int mt = 0; mt < 4; ++mt)
                #pragma unroll
                for (int rg = 0; rg < 4; ++rg) {
                    float sqi = sqiv[mt][rg];
                    unsigned gi = (unsigned)(ibase + wi * 64 + mt * 16 + q * 4 + rg);
                    #pragma unroll
                    for (int nt = 0; nt < 4; ++nt) {
                        float dv = (sqi + sqjv[nt]) - 2.0f * acc[mt][nt][rg];
                        ins3(ct[nt][0], ct[nt][1], ct[nt][2], pack_di(dv, gi));
                    }
                }
            #pragma unroll
            for (int nt = 0; nt < 4; ++nt) {
                #pragma unroll
                for (int m = 16; m < 64; m <<= 1) {
                    u64 b0 = __shfl_xor(ct[nt][0], m, 64);
                    u64 b1 = __shfl_xor(ct[nt][1], m, 64);
                    u64 b2 = __shfl_xor(ct[nt][2], m, 64);
                    merge3(ct[nt][0], ct[nt][1], ct[nt][2], b0, b1, b2);
                }
            }
            if (q == 0) {
                #pragma unroll
                for (int nt = 0; nt < 4; ++nt) {
                    int col = wj * 64 + nt * 16 + lc;
                    u64* cb = &colbuf[col * 6 + wi * 3];
                    cb[0] = ct[nt][0]; cb[1] = ct[nt][1]; cb[2] = ct[nt][2];
                }
            }
        }

        __syncthreads();   // the ONLY epilogue barrier

        if (tid < 128) {
            u64* rb = &rowbuf[tid * 6];
            u64 t0 = rb[0], t1 = rb[1], t2 = rb[2];
            merge3(t0, t1, t2, rb[3], rb[4], rb[5]);
            u64* dp = part + ((size_t)(ibase + tid) * 64 + jt) * 3;
            dp[0] = t0; dp[1] = t1; dp[2] = t2;
        } else if (!diag) {
            int c = tid - 128;
            u64* cb = &colbuf[c * 6];
            u64 t0 = cb[0], t1 = cb[1], t2 = cb[2];
            merge3(t0, t1, t2, cb[3], cb[4], cb[5]);
            u64* dp = part + ((size_t)(jbase + c) * 64 + it) * 3;
            dp[0] = t0; dp[1] = t1; dp[2] = t2;
        }
    }

    // ======== common ticketed tail: replaces the merge_gather launch ========
    __threadfence();                                   // release all prior global writes
    if (tid == 0) tk_s = atomicAdd(done, 1);
    __syncthreads();
    int tk = tk_s;
    if (tk < NTOT - NMERGE) return;
    if (tid == 0) {
        while (__hip_atomic_load(done, __ATOMIC_ACQUIRE, __HIP_MEMORY_SCOPE_AGENT) < NTOT)
            __builtin_amdgcn_s_sleep(2);
    }
    __syncthreads();

    int slice = tk - (NTOT - NMERGE);                  // 0..255 -> rows [slice*32, slice*32+32)
    const float4* h4 = (const float4*)hout;
    #pragma unroll 1
    for (int r8 = 0; r8 < 8; ++r8) {
        int row = slice * 32 + wave * 8 + r8;
        const u64* pr = part + (size_t)row * 192 + lane * 3;
        u64 t0 = pr[0], t1 = pr[1], t2 = pr[2];
        #pragma unroll
        for (int m = 32; m; m >>= 1) {
            u64 b0 = __shfl_xor(t0, m, 64);
            u64 b1 = __shfl_xor(t1, m, 64);
            u64 b2 = __shfl_xor(t2, m, 64);
            merge3(t0, t1, t2, b0, b1, b2);
        }
        int i0 = (int)(t0 & 0xffffffffu);
        int i1 = (int)(t1 & 0xffffffffu);
        int i2 = (int)(t2 & 0xffffffffu);
        float4 a = h4[(size_t)i0 * 64 + lane];
        float4 b = h4[(size_t)i1 * 64 + lane];
        float4 c = h4[(size_t)i2 * 64 + lane];
        float4 o;
        o.x = (a.x + b.x) + c.x;
        o.y = (a.y + b.y) + c.y;
        o.z = (a.z + b.z) + c.z;
        o.w = (a.w + b.w) + c.w;
        ushort4 H, M;
        split2one(o.x, H.x, M.x);
        split2one(o.y, H.y, M.y);
        split2one(o.z, H.z, M.z);
        split2one(o.w, H.w, M.w);
        int i = row * CH + lane * 4;
        *(ushort4*)(gh + i) = H;
        *(ushort4*)(gm + i) = M;
    }
}

// -- fused second stage + linear2: x1 = relu(agg@Wrel^T + brel + h@Wroot^T);
//    out += partial(x1_tile @ W2^T) via atomics (out pre-zeroed; b2 added by nbase==0) --
__global__ __launch_bounds__(256, 2) void gemm2_mfma(
    const unsigned short* __restrict__ Gh, const unsigned short* __restrict__ Gm,
    const unsigned short* __restrict__ Hh, const unsigned short* __restrict__ Hm,
    const unsigned short* __restrict__ Rh, const unsigned short* __restrict__ Rm,
    const unsigned short* __restrict__ Th, const unsigned short* __restrict__ Tm,
    const float* __restrict__ brel, float* __restrict__ x1,
    const float* __restrict__ W2, const float* __restrict__ b2,
    float* __restrict__ out)
{
    __shared__ short sGh[64 * 32], sGm[64 * 32], sHh[64 * 32], sHm[64 * 32];
    __shared__ short sRh[64 * 32], sRm[64 * 32], sTh[64 * 32], sTm[64 * 32];
    int tid = threadIdx.x;
    int wave = tid >> 6, lane = tid & 63;
    int lc = lane & 15, q = lane >> 4;
    int mbase = blockIdx.x * 64, nbase = blockIdx.y * 64;

    f32x4 acc[4];
    #pragma unroll
    for (int nt = 0; nt < 4; ++nt) acc[nt] = (f32x4){0.f, 0.f, 0.f, 0.f};

    int srow = lane >> 2;
    int skq  = ((lane & 3) ^ ((lane >> 3) & 3)) * 8;
    int r0 = wave * 16;

    const unsigned short* gsrc[8];
    short* ldst[8];
    gsrc[0] = Gh + (size_t)(mbase + r0 + srow) * CH + skq;  ldst[0] = &sGh[r0 * 32];
    gsrc[1] = Gm + (size_t)(mbase + r0 + srow) * CH + skq;  ldst[1] = &sGm[r0 * 32];
    gsrc[2] = Hh + (size_t)(mbase + r0 + srow) * CH + skq;  ldst[2] = &sHh[r0 * 32];
    gsrc[3] = Hm + (size_t)(mbase + r0 + srow) * CH + skq;  ldst[3] = &sHm[r0 * 32];
    gsrc[4] = Rh + (size_t)(nbase + r0 + srow) * CH + skq;  ldst[4] = &sRh[r0 * 32];
    gsrc[5] = Rm + (size_t)(nbase + r0 + srow) * CH + skq;  ldst[5] = &sRm[r0 * 32];
    gsrc[6] = Th + (size_t)(nbase + r0 + srow) * CH + skq;  ldst[6] = &sTh[r0 * 32];
    gsrc[7] = Tm + (size_t)(nbase + r0 + srow) * CH + skq;  ldst[7] = &sTm[r0 * 32];
    int cq = (q ^ ((lc >> 1) & 3)) * 8;

    for (int kk = 0; kk < CH; kk += 32) {
        #pragma unroll
        for (int t = 0; t < 8; ++t) { gl_lds16(gsrc[t], ldst[t]); gsrc[t] += 32; }
        __syncthreads();
        s16x8 gH, gM, hH, hM, rH[4], rM[4], tH[4], tM[4];
        int ar = (wave * 16 + lc) * 32 + cq;
        gH = *(const s16x8*)&sGh[ar];
        gM = *(const s16x8*)&sGm[ar];
        hH = *(const s16x8*)&sHh[ar];
        hM = *(const s16x8*)&sHm[ar];
        #pragma unroll
        for (int nt = 0; nt < 4; ++nt) {
            int br = (nt * 16 + lc) * 32 + cq;
            rH[nt] = *(const s16x8*)&sRh[br];
            rM[nt] = *(const s16x8*)&sRm[br];
            tH[nt] = *(const s16x8*)&sTh[br];
            tM[nt] = *(const s16x8*)&sTm[br];
        }
        #pragma unroll
        for (int nt = 0; nt < 4; ++nt) {
            acc[nt] = __builtin_amdgcn_mfma_f32_16x16x32_bf16(gH, rH[nt], acc[nt], 0, 0, 0);
            acc[nt] = __builtin_amdgcn_mfma_f32_16x16x32_bf16(gH, rM[nt], acc[nt], 0, 0, 0);
            acc[nt] = __builtin_amdgcn_mfma_f32_16x16x32_bf16(gM, rH[nt], acc[nt], 0, 0, 0);
            acc[nt] = __builtin_amdgcn_mfma_f32_16x16x32_bf16(hH, tH[nt], acc[nt], 0, 0, 0);
            acc[nt] = __builtin_amdgcn_mfma_f32_16x16x32_bf16(hH, tM[nt], acc[nt], 0, 0, 0);
            acc[nt] = __builtin_amdgcn_mfma_f32_16x16x32_bf16(hM, tH[nt], acc[nt], 0, 0, 0);
        }
        __syncthreads();
    }

    float w20[4], w21[4];
    #pragma unroll
    for (int nt = 0; nt < 4; ++nt) {
        w20[nt] = W2[nbase + nt * 16 + lc];
        w21[nt] = W2[CH + nbase + nt * 16 + lc];
    }
    float s0[4] = {0.f, 0.f, 0.f, 0.f}, s1[4] = {0.f, 0.f, 0.f, 0.f};
    #pragma unroll
    for (int nt = 0; nt < 4; ++nt) {
        float bv = brel[nbase + nt * 16 + lc];
        #pragma unroll
        for (int rg = 0; rg < 4; ++rg) {
            int row = mbase + wave * 16 + q * 4 + rg;
            int col = nbase + nt * 16 + lc;
            float v = fmaxf(acc[nt][rg] + bv, 0.0f);
            x1[(size_t)row * CH + col] = v;
            s0[rg] = fmaf(v, w20[nt], s0[rg]);
            s1[rg] = fmaf(v, w21[nt], s1[rg]);
        }
    }
    #pragma unroll
    for (int rg = 0; rg < 4; ++rg) {
        #pragma unroll
        for (int m = 1; m < 16; m <<= 1) {
            s0[rg] += __shfl_xor(s0[rg], m, 64);
            s1[rg] += __shfl_xor(s1[rg], m, 64);
        }
    }
    if (lc == 0) {
        #pragma unroll
        for (int rg = 0; rg < 4; ++rg) {
            int row = mbase + wave * 16 + q * 4 + rg;
            float o0 = s0[rg], o1 = s1[rg];
            if (nbase == 0) { o0 += b2[0]; o1 += b2[1]; }
            atomicAdd(&out[(size_t)row * 2 + 0], o0);
            atomicAdd(&out[(size_t)row * 2 + 1], o1);
        }
    }
}

extern "C" void kernel_launch(void* const* d_in, const int* in_sizes, int n_in,
                              void* d_out, int out_size, void* d_ws, size_t ws_size,
                              hipStream_t stream) {
    const float* x    = (const float*)d_in[0];
    const float* W1   = (const float*)d_in[1];
    const float* b1   = (const float*)d_in[2];
    const float* Wrel = (const float*)d_in[3];
    const float* brel = (const float*)d_in[4];
    const float* Wroot= (const float*)d_in[5];
    const float* W2   = (const float*)d_in[6];
    const float* b2   = (const float*)d_in[7];

    float* outp = (float*)d_out;            // [8192*2] first
    float* x1   = outp + (size_t)NN * 2;    // [8192*256] second output

    char* ws = (char*)d_ws;
    float* sq = (float*)ws;                                          // 32 KB
    int* done = (int*)(ws + (48ull << 10));                          // ticket counter
    char* base = ws + (64ull << 10);
    unsigned short* pa = (unsigned short*)(base);                    // 4 MB
    unsigned short* pb = (unsigned short*)(base + (4ull  << 20));    // 4 MB
    unsigned short* pc = (unsigned short*)(base + (8ull  << 20));    // 4 MB
    u64* part          = (u64*)          (base + (12ull << 20));     // 12.6 MB (8192*64*3*8)
    char* base2 = base + (12ull << 20) + (13ull << 20);
    float* h           = (float*)(base2);                            // 8 MB
    unsigned short* hh = (unsigned short*)(base2 + (8ull  << 20));   // 4 MB
    unsigned short* hm = (unsigned short*)(base2 + (12ull << 20));   // 4 MB
    unsigned short* xh = (unsigned short*)(base2 + (16ull << 20));   // 4 MB (reused as gh)
    unsigned short* xm = (unsigned short*)(base2 + (20ull << 20));   // 4 MB (reused as gm)
    char* wsp = base2 + (24ull << 20);
    unsigned short* W1h   = (unsigned short*)(wsp);
    unsigned short* W1m   = (unsigned short*)(wsp + 131072);
    unsigned short* Wrelh = (unsigned short*)(wsp + 2 * 131072);
    unsigned short* Wrelm = (unsigned short*)(wsp + 3 * 131072);
    unsigned short* Wrth  = (unsigned short*)(wsp + 4 * 131072);
    unsigned short* Wrtm  = (unsigned short*)(wsp + 5 * 131072);
    unsigned short* gh = xh;   // x splits fully consumed before merge tail runs (done==NTOT)
    unsigned short* gm = xm;

    // 1. fused: softmax -> sq + p splits + x splits + outp/done zeroing, and weight splits
    softmax_split_kernel<<<NN / 4 + 192, 256, 0, stream>>>(
        x, sq, pa, pb, pc, xh, xm, outp, done,
        W1, Wrel, Wroot, W1h, W1m, Wrelh, Wrelm, Wrth, Wrtm);
    // 2. FUSED: dist tiles (2080) + gemm_h backfill (512) + ticketed merge/gather tail
    dist_gemmh_fused<<<NTOT, 256, 0, stream>>>(
        pa, pb, pc, sq, part,
        xh, xm, W1h, W1m, b1, h, hh, hm, gh, gm, done);
    // 3. x1 = relu(agg @ Wrel^T + brel + h @ Wroot^T); out += x1-tile @ W2^T (+b2)
    gemm2_mfma<<<dim3(NN / 64, CH / 64), 256, 0, stream>>>(
        gh, gm, hh, hm, Wrelh, Wrelm, Wrth, Wrtm, brel, x1, W2, b2, outp);
}

// Round 14
// 241.390 us; speedup vs baseline: 2.5223x; 2.5223x over previous
//
#include <hip/hip_runtime.h>
#include <hip/hip_bf16.h>
#include <math.h>

#define NN 8192
#define CH 256
#define NDIST 2080

typedef unsigned long long u64;
typedef __attribute__((ext_vector_type(8))) short s16x8;
typedef __attribute__((ext_vector_type(4))) float f32x4;

__device__ __forceinline__ u64 pack_di(float d, unsigned j) {
    unsigned u = __float_as_uint(d);
    u ^= (unsigned)((int)u >> 31) | 0x80000000u;
    return ((u64)u << 32) | (u64)j;
}

__device__ __forceinline__ void ins3(u64 &t0, u64 &t1, u64 &t2, u64 v) {
    bool c0 = v < t0;
    u64 hi0 = c0 ? t0 : v;
    t0      = c0 ? v  : t0;
    bool c1 = hi0 < t1;
    u64 hi1 = c1 ? t1 : hi0;
    t1      = c1 ? hi0 : t1;
    t2      = hi1 < t2 ? hi1 : t2;
}

__device__ __forceinline__ u64 umin64(u64 a, u64 b) { return a < b ? a : b; }
__device__ __forceinline__ u64 umax64(u64 a, u64 b) { return a < b ? b : a; }

__device__ __forceinline__ void merge3(u64 &a0, u64 &a1, u64 &a2, u64 b0, u64 b1, u64 b2) {
    u64 m0 = umin64(a0, b0), M0 = umax64(a0, b0);
    u64 m1 = umin64(a1, b1);
    u64 m2 = umin64(a2, b2);
    u64 s  = umin64(M0, m1), S = umax64(M0, m1);
    a0 = m0;
    a1 = s;
    a2 = umin64(S, m2);
}

__device__ __forceinline__ void gl_lds16(const void* g, void* l) {
    __builtin_amdgcn_global_load_lds(
        (const __attribute__((address_space(1))) unsigned int*)g,
        (__attribute__((address_space(3))) unsigned int*)l, 16, 0, 0);
}

// ---------------- splits ----------------
__device__ __forceinline__ void split1(float a, unsigned short& h, unsigned short& m, unsigned short& l) {
    __hip_bfloat16 bh = __float2bfloat16(a);
    float fh = __bfloat162float(bh);
    float r = a - fh;
    __hip_bfloat16 bm = __float2bfloat16(r);
    float fm = __bfloat162float(bm);
    __hip_bfloat16 bl = __float2bfloat16(r - fm);
    h = *(unsigned short*)&bh; m = *(unsigned short*)&bm; l = *(unsigned short*)&bl;
}

__device__ __forceinline__ void split2one(float a, unsigned short& h, unsigned short& m) {
    __hip_bfloat16 bh = __float2bfloat16(a);
    float r = a - __bfloat162float(bh);
    __hip_bfloat16 bm = __float2bfloat16(r);
    h = *(unsigned short*)&bh; m = *(unsigned short*)&bm;
}

// ------- fused: softmax + sq + split3(p) + split2(x) + outp zeroing  PLUS weight splits ---
__global__ __launch_bounds__(256) void softmax_split_kernel(
    const float* __restrict__ x, float* __restrict__ sq,
    unsigned short* __restrict__ pa, unsigned short* __restrict__ pb,
    unsigned short* __restrict__ pc, unsigned short* __restrict__ xh,
    unsigned short* __restrict__ xm, float* __restrict__ outp,
    const float* __restrict__ W1, const float* __restrict__ Wrel, const float* __restrict__ Wroot,
    unsigned short* __restrict__ d0h, unsigned short* __restrict__ d0m,
    unsigned short* __restrict__ d1h, unsigned short* __restrict__ d1m,
    unsigned short* __restrict__ d2h, unsigned short* __restrict__ d2m)
{
    if (blockIdx.x >= NN / 4) {
        int wb = blockIdx.x - NN / 4;      // 0..191
        int which = wb >> 6;
        const float* s = (which == 0) ? W1 : (which == 1) ? Wrel : Wroot;
        unsigned short* dh = (which == 0) ? d0h : (which == 1) ? d1h : d2h;
        unsigned short* dm = (which == 0) ? d0m : (which == 1) ? d1m : d2m;
        int i = (wb & 63) * 1024 + threadIdx.x * 4;
        float4 v = *(const float4*)(s + i);
        ushort4 H, M;
        split2one(v.x, H.x, M.x);
        split2one(v.y, H.y, M.y);
        split2one(v.z, H.z, M.z);
        split2one(v.w, H.w, M.w);
        *(ushort4*)(dh + i) = H;
        *(ushort4*)(dm + i) = M;
        return;
    }
    int wave = threadIdx.x >> 6, lane = threadIdx.x & 63;
    int row = blockIdx.x * 4 + wave;
    if (lane == 1) {    // zero the linear2 accumulators for this row (gemm2 is atomic)
        outp[row * 2 + 0] = 0.0f;
        outp[row * 2 + 1] = 0.0f;
    }
    const float4* xr = (const float4*)(x + (size_t)row * CH);
    float4 v = xr[lane];
    int i = row * CH + lane * 4;
    ushort4 XH, XM;
    split2one(v.x, XH.x, XM.x);
    split2one(v.y, XH.y, XM.y);
    split2one(v.z, XH.z, XM.z);
    split2one(v.w, XH.w, XM.w);
    *(ushort4*)(xh + i) = XH;
    *(ushort4*)(xm + i) = XM;
    float m = fmaxf(fmaxf(v.x, v.y), fmaxf(v.z, v.w));
    #pragma unroll
    for (int off = 32; off; off >>= 1) m = fmaxf(m, __shfl_xor(m, off, 64));
    float e0 = expf(v.x - m), e1 = expf(v.y - m), e2 = expf(v.z - m), e3 = expf(v.w - m);
    float s = (e0 + e1) + (e2 + e3);
    #pragma unroll
    for (int off = 32; off; off >>= 1) s += __shfl_xor(s, off, 64);
    float p0 = e0 / s, p1 = e1 / s, p2 = e2 / s, p3 = e3 / s;
    float qv = (p0 * p0 + p1 * p1) + (p2 * p2 + p3 * p3);
    #pragma unroll
    for (int off = 32; off; off >>= 1) qv += __shfl_xor(qv, off, 64);
    if (lane == 0) sq[row] = qv;
    ushort4 H, M, L;
    split1(p0, H.x, M.x, L.x);
    split1(p1, H.y, M.y, L.y);
    split1(p2, H.z, M.z, L.z);
    split1(p3, H.w, M.w, L.w);
    *(ushort4*)(pa + i) = H;
    *(ushort4*)(pb + i) = M;
    *(ushort4*)(pc + i) = L;
}

// ===== FUSED dispatch: blocks [0,2080) = symmetric dist tiles; [2080, 2592) = gemm_h =====
// dist: 128x128 triangular tile, 4 waves (2x2), 6 products; single-barrier epilogue with
// distributed tail merge (rowbuf/colbuf alias the dead sA). XCD-aware tile swizzle:
// tile = (bid&7)*260 + (bid>>3) keeps each XCD's tiles contiguous in triangular order
// (same-it A-rows stay XCD-local in L2). Pure scheduling permutation — bit-identical output.
// gemm_h: 64x64 tile, h = relu(x @ W1^T + b1) + bf16 split of h; LDS aliased into sA.
__global__ __launch_bounds__(256, 3) void dist_gemmh_fused(
    const unsigned short* __restrict__ pa, const unsigned short* __restrict__ pb,
    const unsigned short* __restrict__ pc, const float* __restrict__ sq,
    u64* __restrict__ part,
    const unsigned short* __restrict__ Ah, const unsigned short* __restrict__ Am,
    const unsigned short* __restrict__ Wh, const unsigned short* __restrict__ Wm,
    const float* __restrict__ bias, float* __restrict__ hout,
    unsigned short* __restrict__ oh, unsigned short* __restrict__ om)
{
    __shared__ short sA[3][128 * 32];
    __shared__ short sB[3][128 * 32];

    int tid = threadIdx.x;
    int wave = tid >> 6, lane = tid & 63;
    int lc = lane & 15, q = lane >> 4;
    int srow = lane >> 2;
    int skq  = ((lane & 3) ^ ((lane >> 3) & 3)) * 8;   // XOR-swizzled global 16B slot
    int cq   = (q ^ ((lc >> 1) & 3)) * 8;              // swizzled LDS slot for frag reads

    if (blockIdx.x >= NDIST) {
        // ---------------- gemm_h branch ----------------
        int b = blockIdx.x - NDIST;                    // 0..511
        int mbase = (b & 127) * 64, nbase = (b >> 7) * 64;
        short* sAh = &sA[0][0];
        short* sAm = &sA[0][64 * 32];
        short* sBh = &sA[1][0];
        short* sBm = &sA[1][64 * 32];

        f32x4 acc[4];
        #pragma unroll
        for (int nt = 0; nt < 4; ++nt) acc[nt] = (f32x4){0.f, 0.f, 0.f, 0.f};

        int r0 = wave * 16;
        const unsigned short* gsrc[4];
        short* ldst[4];
        gsrc[0] = Ah + (size_t)(mbase + r0 + srow) * CH + skq;  ldst[0] = &sAh[r0 * 32];
        gsrc[1] = Am + (size_t)(mbase + r0 + srow) * CH + skq;  ldst[1] = &sAm[r0 * 32];
        gsrc[2] = Wh + (size_t)(nbase + r0 + srow) * CH + skq;  ldst[2] = &sBh[r0 * 32];
        gsrc[3] = Wm + (size_t)(nbase + r0 + srow) * CH + skq;  ldst[3] = &sBm[r0 * 32];

        for (int kk = 0; kk < CH; kk += 32) {
            #pragma unroll
            for (int t = 0; t < 4; ++t) { gl_lds16(gsrc[t], ldst[t]); gsrc[t] += 32; }
            __syncthreads();
            s16x8 aH, aM, bH[4], bM[4];
            aH = *(const s16x8*)&sAh[(wave * 16 + lc) * 32 + cq];
            aM = *(const s16x8*)&sAm[(wave * 16 + lc) * 32 + cq];
            #pragma unroll
            for (int nt = 0; nt < 4; ++nt) {
                bH[nt] = *(const s16x8*)&sBh[(nt * 16 + lc) * 32 + cq];
                bM[nt] = *(const s16x8*)&sBm[(nt * 16 + lc) * 32 + cq];
            }
            #pragma unroll
            for (int nt = 0; nt < 4; ++nt)
                acc[nt] = __builtin_amdgcn_mfma_f32_16x16x32_bf16(aH, bH[nt], acc[nt], 0, 0, 0);
            #pragma unroll
            for (int nt = 0; nt < 4; ++nt)
                acc[nt] = __builtin_amdgcn_mfma_f32_16x16x32_bf16(aH, bM[nt], acc[nt], 0, 0, 0);
            #pragma unroll
            for (int nt = 0; nt < 4; ++nt)
                acc[nt] = __builtin_amdgcn_mfma_f32_16x16x32_bf16(aM, bH[nt], acc[nt], 0, 0, 0);
            __syncthreads();
        }

        #pragma unroll
        for (int nt = 0; nt < 4; ++nt) {
            float bv = bias[nbase + nt * 16 + lc];
            #pragma unroll
            for (int rg = 0; rg < 4; ++rg) {
                int row = mbase + wave * 16 + q * 4 + rg;
                int col = nbase + nt * 16 + lc;
                float v = fmaxf(acc[nt][rg] + bv, 0.0f);
                hout[(size_t)row * CH + col] = v;
                unsigned short hh_, hm_;
                split2one(v, hh_, hm_);
                oh[(size_t)row * CH + col] = hh_;
                om[(size_t)row * CH + col] = hm_;
            }
        }
        return;
    }

    // ---------------- dist branch (XCD-swizzled compact triangular id) ----------------
    u64* rowbuf = (u64*)&sA[0][0];          // 128 rows x 2 triples x 3 = 6 KB (sA dead post K-loop)
    u64* colbuf = rowbuf + 128 * 6;         // 128 cols x 2 triples x 3 = 6 KB
    int t = (blockIdx.x & 7) * (NDIST / 8) + (blockIdx.x >> 3);   // XCD-contiguous tiles
    int it = 0;
    while (t >= 64 - it) { t -= 64 - it; ++it; }
    int jt = it + t;
    bool diag = (jt == it);
    int wi = wave >> 1, wj = wave & 1;
    int ibase = it * 128, jbase = jt * 128;

    f32x4 acc[4][4];
    #pragma unroll
    for (int mt = 0; mt < 4; ++mt)
        #pragma unroll
        for (int nt = 0; nt < 4; ++nt)
            acc[mt][nt] = (f32x4){0.f, 0.f, 0.f, 0.f};

    const unsigned short* gsrc[12];
    short* ldst[12];
    {
        const unsigned short* comp[3] = {pa, pb, pc};
        #pragma unroll
        for (int c = 0; c < 3; ++c)
            #pragma unroll
            for (int ch = 0; ch < 2; ++ch) {
                int r0 = (wave * 2 + ch) * 16;
                int n = (c * 2 + ch) * 2;
                gsrc[n + 0] = comp[c] + (size_t)(ibase + r0 + srow) * CH + skq;
                ldst[n + 0] = &sA[c][r0 * 32];
                gsrc[n + 1] = comp[c] + (size_t)(jbase + r0 + srow) * CH + skq;
                ldst[n + 1] = &sB[c][r0 * 32];
            }
    }

    for (int kk = 0; kk < CH; kk += 32) {
        #pragma unroll
        for (int t2 = 0; t2 < 12; ++t2) { gl_lds16(gsrc[t2], ldst[t2]); gsrc[t2] += 32; }
        __syncthreads();

        s16x8 aH[4], bH[4], aM[4], bM[4], aL[4], bL[4];
        #pragma unroll
        for (int mt = 0; mt < 4; ++mt)
            aH[mt] = *(const s16x8*)&sA[0][(wi * 64 + mt * 16 + lc) * 32 + cq];
        #pragma unroll
        for (int nt = 0; nt < 4; ++nt)
            bH[nt] = *(const s16x8*)&sB[0][(wj * 64 + nt * 16 + lc) * 32 + cq];
        #pragma unroll
        for (int mt = 0; mt < 4; ++mt)
            #pragma unroll
            for (int nt = 0; nt < 4; ++nt)
                acc[mt][nt] = __builtin_amdgcn_mfma_f32_16x16x32_bf16(aH[mt], bH[nt], acc[mt][nt], 0, 0, 0);

        #pragma unroll
        for (int nt = 0; nt < 4; ++nt)
            bM[nt] = *(const s16x8*)&sB[1][(wj * 64 + nt * 16 + lc) * 32 + cq];
        #pragma unroll
        for (int mt = 0; mt < 4; ++mt)
            #pragma unroll
            for (int nt = 0; nt < 4; ++nt)
                acc[mt][nt] = __builtin_amdgcn_mfma_f32_16x16x32_bf16(aH[mt], bM[nt], acc[mt][nt], 0, 0, 0);

        #pragma unroll
        for (int mt = 0; mt < 4; ++mt)
            aM[mt] = *(const s16x8*)&sA[1][(wi * 64 + mt * 16 + lc) * 32 + cq];
        #pragma unroll
        for (int mt = 0; mt < 4; ++mt)
            #pragma unroll
            for (int nt = 0; nt < 4; ++nt)
                acc[mt][nt] = __builtin_amdgcn_mfma_f32_16x16x32_bf16(aM[mt], bH[nt], acc[mt][nt], 0, 0, 0);
        #pragma unroll
        for (int mt = 0; mt < 4; ++mt)
            #pragma unroll
            for (int nt = 0; nt < 4; ++nt)
                acc[mt][nt] = __builtin_amdgcn_mfma_f32_16x16x32_bf16(aM[mt], bM[nt], acc[mt][nt], 0, 0, 0);

        #pragma unroll
        for (int nt = 0; nt < 4; ++nt)
            bL[nt] = *(const s16x8*)&sB[2][(wj * 64 + nt * 16 + lc) * 32 + cq];
        #pragma unroll
        for (int mt = 0; mt < 4; ++mt)
            #pragma unroll
            for (int nt = 0; nt < 4; ++nt)
                acc[mt][nt] = __builtin_amdgcn_mfma_f32_16x16x32_bf16(aH[mt], bL[nt], acc[mt][nt], 0, 0, 0);

        #pragma unroll
        for (int mt = 0; mt < 4; ++mt)
            aL[mt] = *(const s16x8*)&sA[2][(wi * 64 + mt * 16 + lc) * 32 + cq];
        #pragma unroll
        for (int mt = 0; mt < 4; ++mt)
            #pragma unroll
            for (int nt = 0; nt < 4; ++nt)
                acc[mt][nt] = __builtin_amdgcn_mfma_f32_16x16x32_bf16(aL[mt], bH[nt], acc[mt][nt], 0, 0, 0);

        __syncthreads();
    }

    // ---- epilogue: D = (sq_i + sq_j) - 2*dot; single barrier + distributed tail ----
    float sqjv[4];
    #pragma unroll
    for (int nt = 0; nt < 4; ++nt) sqjv[nt] = sq[jbase + wj * 64 + nt * 16 + lc];
    float sqiv[4][4];
    #pragma unroll
    for (int mt = 0; mt < 4; ++mt)
        #pragma unroll
        for (int rg = 0; rg < 4; ++rg)
            sqiv[mt][rg] = sq[ibase + wi * 64 + mt * 16 + q * 4 + rg];

    // row-wise: per-row in-lane top3 + lc-butterfly; both wj waves deposit to rowbuf
    #pragma unroll
    for (int mt = 0; mt < 4; ++mt) {
        #pragma unroll
        for (int rg = 0; rg < 4; ++rg) {
            float sqi = sqiv[mt][rg];
            u64 t0 = ~0ULL, t1 = ~0ULL, t2 = ~0ULL;
            #pragma unroll
            for (int nt = 0; nt < 4; ++nt) {
                float dv = (sqi + sqjv[nt]) - 2.0f * acc[mt][nt][rg];
                unsigned col = (unsigned)(jbase + wj * 64 + nt * 16 + lc);
                ins3(t0, t1, t2, pack_di(dv, col));
            }
            #pragma unroll
            for (int m = 1; m < 16; m <<= 1) {
                u64 b0 = __shfl_xor(t0, m, 64);
                u64 b1 = __shfl_xor(t1, m, 64);
                u64 b2 = __shfl_xor(t2, m, 64);
                merge3(t0, t1, t2, b0, b1, b2);
            }
            if (lc == 0) {
                int r = wi * 64 + mt * 16 + q * 4 + rg;
                u64* rb = &rowbuf[r * 6 + wj * 3];
                rb[0] = t0; rb[1] = t1; rb[2] = t2;
            }
        }
    }

    // col-wise (off-diag only): both wi waves deposit to colbuf
    if (!diag) {
        u64 ct[4][3];
        #pragma unroll
        for (int nt = 0; nt < 4; ++nt) { ct[nt][0] = ~0ULL; ct[nt][1] = ~0ULL; ct[nt][2] = ~0ULL; }
        #pragma unroll
        for (int mt = 0; mt < 4; ++mt)
            #pragma unroll
            for (int rg = 0; rg < 4; ++rg) {
                float sqi = sqiv[mt][rg];
                unsigned gi = (unsigned)(ibase + wi * 64 + mt * 16 + q * 4 + rg);
                #pragma unroll
                for (int nt = 0; nt < 4; ++nt) {
                    float dv = (sqi + sqjv[nt]) - 2.0f * acc[mt][nt][rg];
                    ins3(ct[nt][0], ct[nt][1], ct[nt][2], pack_di(dv, gi));
                }
            }
        #pragma unroll
        for (int nt = 0; nt < 4; ++nt) {
            #pragma unroll
            for (int m = 16; m < 64; m <<= 1) {
                u64 b0 = __shfl_xor(ct[nt][0], m, 64);
                u64 b1 = __shfl_xor(ct[nt][1], m, 64);
                u64 b2 = __shfl_xor(ct[nt][2], m, 64);
                merge3(ct[nt][0], ct[nt][1], ct[nt][2], b0, b1, b2);
            }
        }
        if (q == 0) {
            #pragma unroll
            for (int nt = 0; nt < 4; ++nt) {
                int col = wj * 64 + nt * 16 + lc;
                u64* cb = &colbuf[col * 6 + wi * 3];
                cb[0] = ct[nt][0]; cb[1] = ct[nt][1]; cb[2] = ct[nt][2];
            }
        }
    }

    __syncthreads();   // the ONLY epilogue barrier

    // distributed tail: threads 0..127 -> rows; 128..255 -> cols
    if (tid < 128) {
        u64* rb = &rowbuf[tid * 6];
        u64 t0 = rb[0], t1 = rb[1], t2 = rb[2];
        merge3(t0, t1, t2, rb[3], rb[4], rb[5]);
        u64* dp = part + ((size_t)(ibase + tid) * 64 + jt) * 3;
        dp[0] = t0; dp[1] = t1; dp[2] = t2;
    } else if (!diag) {
        int c = tid - 128;
        u64* cb = &colbuf[c * 6];
        u64 t0 = cb[0], t1 = cb[1], t2 = cb[2];
        merge3(t0, t1, t2, cb[3], cb[4], cb[5]);
        u64* dp = part + ((size_t)(jbase + c) * 64 + it) * 3;
        dp[0] = t0; dp[1] = t1; dp[2] = t2;
    }
}

// -- fused second stage + linear2: x1 = relu(agg@Wrel^T + brel + h@Wroot^T);
//    out += partial(x1_tile @ W2^T) via atomics (out pre-zeroed; b2 added by nbase==0) --
__global__ __launch_bounds__(256, 2) void gemm2_mfma(
    const unsigned short* __restrict__ Gh, const unsigned short* __restrict__ Gm,
    const unsigned short* __restrict__ Hh, const unsigned short* __restrict__ Hm,
    const unsigned short* __restrict__ Rh, const unsigned short* __restrict__ Rm,
    const unsigned short* __restrict__ Th, const unsigned short* __restrict__ Tm,
    const float* __restrict__ brel, float* __restrict__ x1,
    const float* __restrict__ W2, const float* __restrict__ b2,
    float* __restrict__ out)
{
    __shared__ short sGh[64 * 32], sGm[64 * 32], sHh[64 * 32], sHm[64 * 32];
    __shared__ short sRh[64 * 32], sRm[64 * 32], sTh[64 * 32], sTm[64 * 32];
    int tid = threadIdx.x;
    int wave = tid >> 6, lane = tid & 63;
    int lc = lane & 15, q = lane >> 4;
    int mbase = blockIdx.x * 64, nbase = blockIdx.y * 64;

    f32x4 acc[4];
    #pragma unroll
    for (int nt = 0; nt < 4; ++nt) acc[nt] = (f32x4){0.f, 0.f, 0.f, 0.f};

    int srow = lane >> 2;
    int skq  = ((lane & 3) ^ ((lane >> 3) & 3)) * 8;
    int r0 = wave * 16;

    const unsigned short* gsrc[8];
    short* ldst[8];
    gsrc[0] = Gh + (size_t)(mbase + r0 + srow) * CH + skq;  ldst[0] = &sGh[r0 * 32];
    gsrc[1] = Gm + (size_t)(mbase + r0 + srow) * CH + skq;  ldst[1] = &sGm[r0 * 32];
    gsrc[2] = Hh + (size_t)(mbase + r0 + srow) * CH + skq;  ldst[2] = &sHh[r0 * 32];
    gsrc[3] = Hm + (size_t)(mbase + r0 + srow) * CH + skq;  ldst[3] = &sHm[r0 * 32];
    gsrc[4] = Rh + (size_t)(nbase + r0 + srow) * CH + skq;  ldst[4] = &sRh[r0 * 32];
    gsrc[5] = Rm + (size_t)(nbase + r0 + srow) * CH + skq;  ldst[5] = &sRm[r0 * 32];
    gsrc[6] = Th + (size_t)(nbase + r0 + srow) * CH + skq;  ldst[6] = &sTh[r0 * 32];
    gsrc[7] = Tm + (size_t)(nbase + r0 + srow) * CH + skq;  ldst[7] = &sTm[r0 * 32];
    int cq = (q ^ ((lc >> 1) & 3)) * 8;

    for (int kk = 0; kk < CH; kk += 32) {
        #pragma unroll
        for (int t = 0; t < 8; ++t) { gl_lds16(gsrc[t], ldst[t]); gsrc[t] += 32; }
        __syncthreads();
        s16x8 gH, gM, hH, hM, rH[4], rM[4], tH[4], tM[4];
        int ar = (wave * 16 + lc) * 32 + cq;
        gH = *(const s16x8*)&sGh[ar];
        gM = *(const s16x8*)&sGm[ar];
        hH = *(const s16x8*)&sHh[ar];
        hM = *(const s16x8*)&sHm[ar];
        #pragma unroll
        for (int nt = 0; nt < 4; ++nt) {
            int br = (nt * 16 + lc) * 32 + cq;
            rH[nt] = *(const s16x8*)&sRh[br];
            rM[nt] = *(const s16x8*)&sRm[br];
            tH[nt] = *(const s16x8*)&sTh[br];
            tM[nt] = *(const s16x8*)&sTm[br];
        }
        #pragma unroll
        for (int nt = 0; nt < 4; ++nt) {
            acc[nt] = __builtin_amdgcn_mfma_f32_16x16x32_bf16(gH, rH[nt], acc[nt], 0, 0, 0);
            acc[nt] = __builtin_amdgcn_mfma_f32_16x16x32_bf16(gH, rM[nt], acc[nt], 0, 0, 0);
            acc[nt] = __builtin_amdgcn_mfma_f32_16x16x32_bf16(gM, rH[nt], acc[nt], 0, 0, 0);
            acc[nt] = __builtin_amdgcn_mfma_f32_16x16x32_bf16(hH, tH[nt], acc[nt], 0, 0, 0);
            acc[nt] = __builtin_amdgcn_mfma_f32_16x16x32_bf16(hH, tM[nt], acc[nt], 0, 0, 0);
            acc[nt] = __builtin_amdgcn_mfma_f32_16x16x32_bf16(hM, tH[nt], acc[nt], 0, 0, 0);
        }
        __syncthreads();
    }

    float w20[4], w21[4];
    #pragma unroll
    for (int nt = 0; nt < 4; ++nt) {
        w20[nt] = W2[nbase + nt * 16 + lc];
        w21[nt] = W2[CH + nbase + nt * 16 + lc];
    }
    float s0[4] = {0.f, 0.f, 0.f, 0.f}, s1[4] = {0.f, 0.f, 0.f, 0.f};
    #pragma unroll
    for (int nt = 0; nt < 4; ++nt) {
        float bv = brel[nbase + nt * 16 + lc];
        #pragma unroll
        for (int rg = 0; rg < 4; ++rg) {
            int row = mbase + wave * 16 + q * 4 + rg;
            int col = nbase + nt * 16 + lc;
            float v = fmaxf(acc[nt][rg] + bv, 0.0f);
            x1[(size_t)row * CH + col] = v;
            s0[rg] = fmaf(v, w20[nt], s0[rg]);
            s1[rg] = fmaf(v, w21[nt], s1[rg]);
        }
    }
    #pragma unroll
    for (int rg = 0; rg < 4; ++rg) {
        #pragma unroll
        for (int m = 1; m < 16; m <<= 1) {
            s0[rg] += __shfl_xor(s0[rg], m, 64);
            s1[rg] += __shfl_xor(s1[rg], m, 64);
        }
    }
    if (lc == 0) {
        #pragma unroll
        for (int rg = 0; rg < 4; ++rg) {
            int row = mbase + wave * 16 + q * 4 + rg;
            float o0 = s0[rg], o1 = s1[rg];
            if (nbase == 0) { o0 += b2[0]; o1 += b2[1]; }
            atomicAdd(&out[(size_t)row * 2 + 0], o0);
            atomicAdd(&out[(size_t)row * 2 + 1], o1);
        }
    }
}

// ---------------- merge 64 partial top-3s per row, gather+sum h rows, emit agg splits ----
__global__ __launch_bounds__(256) void merge_gather_split(
    const u64* __restrict__ part, const float* __restrict__ h,
    unsigned short* __restrict__ gh, unsigned short* __restrict__ gm)
{
    int wave = threadIdx.x >> 6, lane = threadIdx.x & 63;
    int row = blockIdx.x * 4 + wave;
    const u64* pr = part + (size_t)row * 192 + lane * 3;
    u64 t0 = pr[0], t1 = pr[1], t2 = pr[2];
    #pragma unroll
    for (int m = 32; m; m >>= 1) {
        u64 b0 = __shfl_xor(t0, m, 64);
        u64 b1 = __shfl_xor(t1, m, 64);
        u64 b2 = __shfl_xor(t2, m, 64);
        merge3(t0, t1, t2, b0, b1, b2);
    }
    int i0 = (int)(t0 & 0xffffffffu);
    int i1 = (int)(t1 & 0xffffffffu);
    int i2 = (int)(t2 & 0xffffffffu);
    const float4* h4 = (const float4*)h;
    float4 a = h4[(size_t)i0 * 64 + lane];
    float4 b = h4[(size_t)i1 * 64 + lane];
    float4 c = h4[(size_t)i2 * 64 + lane];
    float4 o;
    o.x = (a.x + b.x) + c.x;
    o.y = (a.y + b.y) + c.y;
    o.z = (a.z + b.z) + c.z;
    o.w = (a.w + b.w) + c.w;
    ushort4 H, M;
    split2one(o.x, H.x, M.x);
    split2one(o.y, H.y, M.y);
    split2one(o.z, H.z, M.z);
    split2one(o.w, H.w, M.w);
    int i = row * CH + lane * 4;
    *(ushort4*)(gh + i) = H;
    *(ushort4*)(gm + i) = M;
}

extern "C" void kernel_launch(void* const* d_in, const int* in_sizes, int n_in,
                              void* d_out, int out_size, void* d_ws, size_t ws_size,
                              hipStream_t stream) {
    const float* x    = (const float*)d_in[0];
    const float* W1   = (const float*)d_in[1];
    const float* b1   = (const float*)d_in[2];
    const float* Wrel = (const float*)d_in[3];
    const float* brel = (const float*)d_in[4];
    const float* Wroot= (const float*)d_in[5];
    const float* W2   = (const float*)d_in[6];
    const float* b2   = (const float*)d_in[7];

    float* outp = (float*)d_out;            // [8192*2] first
    float* x1   = outp + (size_t)NN * 2;    // [8192*256] second output

    char* ws = (char*)d_ws;
    float* sq = (float*)ws;                                          // 32 KB (pad to 64K)
    char* base = ws + (64ull << 10);
    unsigned short* pa = (unsigned short*)(base);                    // 4 MB
    unsigned short* pb = (unsigned short*)(base + (4ull  << 20));    // 4 MB
    unsigned short* pc = (unsigned short*)(base + (8ull  << 20));    // 4 MB
    u64* part          = (u64*)          (base + (12ull << 20));     // 12.6 MB (8192*64*3*8)
    char* base2 = base + (12ull << 20) + (13ull << 20);
    float* h           = (float*)(base2);                            // 8 MB
    unsigned short* hh = (unsigned short*)(base2 + (8ull  << 20));   // 4 MB
    unsigned short* hm = (unsigned short*)(base2 + (12ull << 20));   // 4 MB
    unsigned short* xh = (unsigned short*)(base2 + (16ull << 20));   // 4 MB (reused as gh)
    unsigned short* xm = (unsigned short*)(base2 + (20ull << 20));   // 4 MB (reused as gm)
    char* wsp = base2 + (24ull << 20);
    unsigned short* W1h   = (unsigned short*)(wsp);
    unsigned short* W1m   = (unsigned short*)(wsp + 131072);
    unsigned short* Wrelh = (unsigned short*)(wsp + 2 * 131072);
    unsigned short* Wrelm = (unsigned short*)(wsp + 3 * 131072);
    unsigned short* Wrth  = (unsigned short*)(wsp + 4 * 131072);
    unsigned short* Wrtm  = (unsigned short*)(wsp + 5 * 131072);
    unsigned short* gh = xh;               // x splits dead after gemm_h branch
    unsigned short* gm = xm;

    // 1. fused: softmax -> sq + p splits + x splits + outp zeroing, and weight splits
    softmax_split_kernel<<<NN / 4 + 192, 256, 0, stream>>>(
        x, sq, pa, pb, pc, xh, xm, outp,
        W1, Wrel, Wroot, W1h, W1m, Wrelh, Wrelm, Wrth, Wrtm);
    // 2. FUSED: dist tiles (2080, XCD-swizzled dynamic dispatch) + gemm_h backfill (512)
    dist_gemmh_fused<<<NDIST + 512, 256, 0, stream>>>(
        pa, pb, pc, sq, part,
        xh, xm, W1h, W1m, b1, h, hh, hm);
    // 3. global top3 merge + gather-sum of h rows, fused split of agg
    merge_gather_split<<<NN / 4, 256, 0, stream>>>(part, h, gh, gm);
    // 4. x1 = relu(agg @ Wrel^T + brel + h @ Wroot^T); out += x1-tile @ W2^T (+b2)
    gemm2_mfma<<<dim3(NN / 64, CH / 64), 256, 0, stream>>>(
        gh, gm, hh, hm, Wrelh, Wrelm, Wrth, Wrtm, brel, x1, W2, b2, outp);
}